// Round 3
// baseline (694.284 us; speedup 1.0000x reference)
//
#include <hip/hip_runtime.h>
#include <stdint.h>

#define L_NR 192
#define S_NS 256
#define D_   256
#define H_   8
#define C_   32
#define NEG_INF_F (-10000.0f)

typedef __bf16 bf16x8_t __attribute__((ext_vector_type(8)));
typedef float  f32x4_t  __attribute__((ext_vector_type(4)));

__device__ __forceinline__ float bflo(unsigned int u) { return __uint_as_float(u << 16); }
__device__ __forceinline__ float bfhi(unsigned int u) { return __uint_as_float(u & 0xffff0000u); }
__device__ __forceinline__ unsigned int f2b(float f) {
    unsigned int x = __float_as_uint(f);
    return (x + 0x7fffu + ((x >> 16) & 1u)) >> 16;   // RNE
}

// ---- Convert 5 fp32 weight matrices (256x256) to bf16 in workspace ----
__global__ __launch_bounds__(256) void convw_kernel(
    const float* __restrict__ wq, const float* __restrict__ wk,
    const float* __restrict__ wv, const float* __restrict__ wg,
    const float* __restrict__ wo, unsigned short* __restrict__ dst)
{
    int mat = blockIdx.y;
    const float* src = (mat == 0) ? wq : (mat == 1) ? wk : (mat == 2) ? wv
                     : (mat == 3) ? wg : wo;
    int i = (blockIdx.x * 256 + threadIdx.x) * 4;          // 0..65532
    float4 v = *(const float4*)(src + i);
    uint2 w;
    w.x = f2b(v.x) | (f2b(v.y) << 16);
    w.y = f2b(v.z) | (f2b(v.w) << 16);
    *(uint2*)(dst + (size_t)mat * 65536 + i) = w;
}

// ---------------- LayerNorm: m fp32 (S,L,D) -> xn bf16 (L,S,D) ----------------
__global__ __launch_bounds__(256) void ln_kernel(
    const float* __restrict__ m,
    const float* __restrict__ lns,
    const float* __restrict__ lnb,
    unsigned short* __restrict__ xn)
{
    int tid = threadIdx.x;
    int lane = tid & 63, wave = tid >> 6;
    int r = blockIdx.x * 4 + wave;          // r = s*L + l
    int s = r / L_NR, l = r % L_NR;

    float4 x = ((const float4*)(m + (size_t)r * D_))[lane];

    float sum = x.x + x.y + x.z + x.w;
    float ss  = x.x*x.x + x.y*x.y + x.z*x.z + x.w*x.w;
#pragma unroll
    for (int off = 32; off > 0; off >>= 1) {
        sum += __shfl_xor(sum, off, 64);
        ss  += __shfl_xor(ss,  off, 64);
    }
    float mean = sum * (1.0f/256.0f);
    float var  = ss  * (1.0f/256.0f) - mean * mean;
    float rstd = rsqrtf(fmaxf(var, 0.0f) + 1e-5f);

    float4 sc = ((const float4*)lns)[lane];
    float4 bi = ((const float4*)lnb)[lane];

    float y0 = (x.x - mean) * rstd * sc.x + bi.x;
    float y1 = (x.y - mean) * rstd * sc.y + bi.y;
    float y2 = (x.z - mean) * rstd * sc.z + bi.z;
    float y3 = (x.w - mean) * rstd * sc.w + bi.w;

    uint2 w;
    w.x = f2b(y0) | (f2b(y1) << 16);
    w.y = f2b(y2) | (f2b(y3) << 16);
    *(uint2*)(xn + ((size_t)l * S_NS + s) * D_ + lane * 4) = w;
}

// ------------- Projections: xn @ W^T -> q,k,v,g bf16 in (L,H,S,C) -------------
__global__ __launch_bounds__(256) void proj_kernel(
    const unsigned short* __restrict__ xn,
    const unsigned short* __restrict__ wbf,   // 4 matrices, bf16, 65536 each
    const float* __restrict__ bg,
    unsigned short* __restrict__ qb, unsigned short* __restrict__ kb,
    unsigned short* __restrict__ vb, unsigned short* __restrict__ gb)
{
    int tid  = threadIdx.x;
    int lane = tid & 63, wave = tid >> 6;
    int quad = lane >> 4, l16 = lane & 15;
    int m0   = blockIdx.x * 64 + wave * 16;
    int mat  = blockIdx.y;
    const unsigned short* W = wbf + (size_t)mat * 65536;

    f32x4_t acc[16];
#pragma unroll
    for (int i = 0; i < 16; ++i) acc[i] = (f32x4_t){0.f, 0.f, 0.f, 0.f};

    const unsigned short* arow = xn + (size_t)(m0 + l16) * D_ + quad * 8;
    const unsigned short* brow = W  + (size_t)l16 * D_ + quad * 8;

    for (int ks = 0; ks < 256; ks += 32) {
        bf16x8_t af = *(const bf16x8_t*)(arow + ks);
#pragma unroll
        for (int i = 0; i < 16; ++i) {
            bf16x8_t bf = *(const bf16x8_t*)(brow + (size_t)i * 16 * D_ + ks);
            acc[i] = __builtin_amdgcn_mfma_f32_16x16x32_bf16(af, bf, acc[i], 0, 0, 0);
        }
    }

    const float qscale = 0.17677669529663687f;  // 1/sqrt(32)
#pragma unroll
    for (int i = 0; i < 16; ++i) {
        int n = i * 16 + l16;          // output col 0..255
        int h = n >> 5, c = n & 31;
        float bgn = (mat == 3) ? bg[n] : 0.0f;
#pragma unroll
        for (int r = 0; r < 4; ++r) {
            int mrow = m0 + quad * 4 + r;
            int l = mrow >> 8, s = mrow & 255;
            size_t idx = ((size_t)(l * H_ + h) * S_NS + s) * C_ + c;
            float v = acc[i][r];
            if (mat == 0)      qb[idx] = (unsigned short)f2b(v * qscale);
            else if (mat == 1) kb[idx] = (unsigned short)f2b(v);
            else if (mat == 2) vb[idx] = (unsigned short)f2b(v);
            else {
                float z = v + bgn;
                gb[idx] = (unsigned short)f2b(1.0f / (1.0f + __expf(-z)));
            }
        }
    }
}

// ------------- Attention per (l,h): online-softmax(qk^T + bias) v * g -------------
__global__ __launch_bounds__(256) void attn_kernel(
    const unsigned short* __restrict__ qb, const unsigned short* __restrict__ kb,
    const unsigned short* __restrict__ vb, const unsigned short* __restrict__ gb,
    const int* __restrict__ seq_pad, const int* __restrict__ res_pad,
    unsigned short* __restrict__ ctxg)
{
    __shared__ __align__(16) float        kld[S_NS * C_];   // fp32 K: 32 KB
    __shared__ __align__(16) unsigned int vld[S_NS * C_/2]; // packed bf16 V: 16 KB
    __shared__ float sbias[S_NS];

    int tid = threadIdx.x;
    int lh  = blockIdx.x;        // l*8 + h
    int l   = lh >> 3;
    size_t base = (size_t)lh * S_NS * C_;

#pragma unroll
    for (int i = 0; i < 8; ++i) {
        int off = i * 1024 + tid * 4;
        uint2 rk = *(const uint2*)(kb + base + off);
        f32x4_t k4;
        k4[0] = bflo(rk.x); k4[1] = bfhi(rk.x); k4[2] = bflo(rk.y); k4[3] = bfhi(rk.y);
        *(f32x4_t*)&kld[off] = k4;
    }
    const uint4* vsrc = (const uint4*)(vb + base);
#pragma unroll
    for (int i = 0; i < 4; ++i) {
        int idx = i * 256 + tid;
        *(uint4*)&vld[idx * 4] = vsrc[idx];
    }

    int rl = res_pad[l];
    sbias[tid] = (rl != 0 || seq_pad[tid] != 0) ? NEG_INF_F : 0.0f;
    __syncthreads();

    int s = tid;
    float qr[32];
    const unsigned short* qp = qb + base + (size_t)s * C_;
#pragma unroll
    for (int i = 0; i < 8; ++i) {
        uint2 rq = *(const uint2*)(qp + i * 4);
        qr[i*4+0] = bflo(rq.x); qr[i*4+1] = bfhi(rq.x);
        qr[i*4+2] = bflo(rq.y); qr[i*4+3] = bfhi(rq.y);
    }

    float ctx[32];
#pragma unroll
    for (int c = 0; c < 32; ++c) ctx[c] = 0.0f;
    float sum  = 0.0f;
    float mrun = -3.0e38f;

    for (int t = 0; t < S_NS; ++t) {
        const float* kr = &kld[t * C_];
        float d = 0.0f;
#pragma unroll
        for (int j = 0; j < 8; ++j) {
            f32x4_t k4 = *(const f32x4_t*)(kr + j * 4);
            d += qr[j*4+0]*k4[0] + qr[j*4+1]*k4[1] + qr[j*4+2]*k4[2] + qr[j*4+3]*k4[3];
        }
        float dz    = d + sbias[t];
        float mnew  = fmaxf(mrun, dz);
        float scale = __expf(mrun - mnew);
        float p     = __expf(dz - mnew);
        sum  = sum * scale + p;
        mrun = mnew;
        const unsigned int* vr = &vld[t * (C_/2)];
#pragma unroll
        for (int j = 0; j < 4; ++j) {
            uint4 u4 = *(const uint4*)(vr + j * 4);
            int c = j * 8;
            ctx[c+0] = ctx[c+0]*scale + p * bflo(u4.x);
            ctx[c+1] = ctx[c+1]*scale + p * bfhi(u4.x);
            ctx[c+2] = ctx[c+2]*scale + p * bflo(u4.y);
            ctx[c+3] = ctx[c+3]*scale + p * bfhi(u4.y);
            ctx[c+4] = ctx[c+4]*scale + p * bflo(u4.z);
            ctx[c+5] = ctx[c+5]*scale + p * bfhi(u4.z);
            ctx[c+6] = ctx[c+6]*scale + p * bflo(u4.w);
            ctx[c+7] = ctx[c+7]*scale + p * bfhi(u4.w);
        }
    }

    float inv = 1.0f / sum;    // sum >= 1 always
    int h = lh & 7;
    const unsigned short* gp = gb + base + (size_t)s * C_;
    unsigned short* op = ctxg + ((size_t)l * S_NS + s) * D_ + h * C_;
#pragma unroll
    for (int i = 0; i < 8; ++i) {
        uint2 rg = *(const uint2*)(gp + i * 4);
        float g0 = bflo(rg.x), g1 = bfhi(rg.x), g2 = bflo(rg.y), g3 = bfhi(rg.y);
        uint2 w;
        w.x = f2b(ctx[i*4+0]*inv*g0) | (f2b(ctx[i*4+1]*inv*g1) << 16);
        w.y = f2b(ctx[i*4+2]*inv*g2) | (f2b(ctx[i*4+3]*inv*g3) << 16);
        *(uint2*)(op + i * 4) = w;
    }
}

// ------------- Output projection: ctxg @ wo^T + bo -> out fp32 (S,L,D) -------------
__global__ __launch_bounds__(256) void out_kernel(
    const unsigned short* __restrict__ ctxg,
    const unsigned short* __restrict__ wob,   // bf16 wo
    const float* __restrict__ bo,
    float* __restrict__ out)
{
    int tid  = threadIdx.x;
    int lane = tid & 63, wave = tid >> 6;
    int quad = lane >> 4, l16 = lane & 15;
    int m0   = blockIdx.x * 64 + wave * 16;

    f32x4_t acc[16];
#pragma unroll
    for (int i = 0; i < 16; ++i) acc[i] = (f32x4_t){0.f, 0.f, 0.f, 0.f};

    const unsigned short* arow = ctxg + (size_t)(m0 + l16) * D_ + quad * 8;
    const unsigned short* brow = wob  + (size_t)l16 * D_ + quad * 8;

    for (int ks = 0; ks < 256; ks += 32) {
        bf16x8_t af = *(const bf16x8_t*)(arow + ks);
#pragma unroll
        for (int i = 0; i < 16; ++i) {
            bf16x8_t bf = *(const bf16x8_t*)(brow + (size_t)i * 16 * D_ + ks);
            acc[i] = __builtin_amdgcn_mfma_f32_16x16x32_bf16(af, bf, acc[i], 0, 0, 0);
        }
    }

#pragma unroll
    for (int i = 0; i < 16; ++i) {
        int n = i * 16 + l16;
        float bias = bo[n];
#pragma unroll
        for (int r = 0; r < 4; ++r) {
            int mrow = m0 + quad * 4 + r;
            int l = mrow >> 8, s = mrow & 255;
            out[((size_t)s * L_NR + l) * D_ + n] = acc[i][r] + bias;
        }
    }
}

extern "C" void kernel_launch(void* const* d_in, const int* in_sizes, int n_in,
                              void* d_out, int out_size, void* d_ws, size_t ws_size,
                              hipStream_t stream) {
    const float* m   = (const float*)d_in[0];
    const int* seq_pad = (const int*)d_in[1];
    const int* res_pad = (const int*)d_in[2];
    const float* lns = (const float*)d_in[3];
    const float* lnb = (const float*)d_in[4];
    const float* wq  = (const float*)d_in[5];
    const float* wk  = (const float*)d_in[6];
    const float* wv  = (const float*)d_in[7];
    const float* wg  = (const float*)d_in[8];
    const float* bg  = (const float*)d_in[9];
    const float* wo  = (const float*)d_in[10];
    const float* bo  = (const float*)d_in[11];
    float* out       = (float*)d_out;

    const size_t NE = (size_t)L_NR * S_NS * D_;   // 12,582,912 elements
    unsigned short* xn = (unsigned short*)d_ws;   // bf16 (L,S,D); reused as ctxg
    unsigned short* qb = xn + NE;
    unsigned short* kb = qb + NE;
    unsigned short* vb = kb + NE;
    unsigned short* gb = vb + NE;
    unsigned short* wbf = gb + NE;                // 5 x 65536 bf16 weights
    unsigned short* ctxg = xn;                    // attn no longer needs xn

    convw_kernel<<<dim3(64, 5), 256, 0, stream>>>(wq, wk, wv, wg, wo, wbf);
    ln_kernel<<<12288, 256, 0, stream>>>(m, lns, lnb, xn);
    proj_kernel<<<dim3(768, 4), 256, 0, stream>>>(xn, wbf, bg, qb, kb, vb, gb);
    attn_kernel<<<L_NR * H_, 256, 0, stream>>>(qb, kb, vb, gb, seq_pad, res_pad, ctxg);
    out_kernel<<<768, 256, 0, stream>>>(ctxg, wbf + 4 * 65536, bo, out);
}

// Round 4
// 474.718 us; speedup vs baseline: 1.4625x; 1.4625x over previous
//
#include <hip/hip_runtime.h>
#include <stdint.h>

#define L_NR 192
#define S_NS 256
#define D_   256
#define H_   8
#define C_   32

typedef __bf16    bf16x8_t __attribute__((ext_vector_type(8)));
typedef _Float16  half4_t  __attribute__((ext_vector_type(4)));
typedef float     f32x4_t  __attribute__((ext_vector_type(4)));

__device__ __forceinline__ float bflo(unsigned int u) { return __uint_as_float(u << 16); }
__device__ __forceinline__ float bfhi(unsigned int u) { return __uint_as_float(u & 0xffff0000u); }
__device__ __forceinline__ unsigned int f2b(float f) {
    unsigned int x = __float_as_uint(f);
    return (x + 0x7fffu + ((x >> 16) & 1u)) >> 16;   // RNE
}
__device__ __forceinline__ unsigned short f2h(float f) {
    union { _Float16 h; unsigned short u; } cv; cv.h = (_Float16)f; return cv.u;
}

// ---- Convert 5 fp32 weight matrices (256x256) to bf16 in workspace ----
__global__ __launch_bounds__(256) void convw_kernel(
    const float* __restrict__ wq, const float* __restrict__ wk,
    const float* __restrict__ wv, const float* __restrict__ wg,
    const float* __restrict__ wo, unsigned short* __restrict__ dst)
{
    int mat = blockIdx.y;
    const float* src = (mat == 0) ? wq : (mat == 1) ? wk : (mat == 2) ? wv
                     : (mat == 3) ? wg : wo;
    int i = (blockIdx.x * 256 + threadIdx.x) * 4;
    float4 v = *(const float4*)(src + i);
    uint2 w;
    w.x = f2b(v.x) | (f2b(v.y) << 16);
    w.y = f2b(v.z) | (f2b(v.w) << 16);
    *(uint2*)(dst + (size_t)mat * 65536 + i) = w;
}

// ---------------- LayerNorm: m fp32 (S,L,D) -> xn bf16 (L,S,D) ----------------
__global__ __launch_bounds__(256) void ln_kernel(
    const float* __restrict__ m,
    const float* __restrict__ lns,
    const float* __restrict__ lnb,
    unsigned short* __restrict__ xn)
{
    int tid = threadIdx.x;
    int lane = tid & 63, wave = tid >> 6;
    int r = blockIdx.x * 4 + wave;          // r = s*L + l
    int s = r / L_NR, l = r % L_NR;

    float4 x = ((const float4*)(m + (size_t)r * D_))[lane];

    float sum = x.x + x.y + x.z + x.w;
    float ss  = x.x*x.x + x.y*x.y + x.z*x.z + x.w*x.w;
#pragma unroll
    for (int off = 32; off > 0; off >>= 1) {
        sum += __shfl_xor(sum, off, 64);
        ss  += __shfl_xor(ss,  off, 64);
    }
    float mean = sum * (1.0f/256.0f);
    float var  = ss  * (1.0f/256.0f) - mean * mean;
    float rstd = rsqrtf(fmaxf(var, 0.0f) + 1e-5f);

    float4 sc = ((const float4*)lns)[lane];
    float4 bi = ((const float4*)lnb)[lane];

    float y0 = (x.x - mean) * rstd * sc.x + bi.x;
    float y1 = (x.y - mean) * rstd * sc.y + bi.y;
    float y2 = (x.z - mean) * rstd * sc.z + bi.z;
    float y3 = (x.w - mean) * rstd * sc.w + bi.w;

    uint2 w;
    w.x = f2b(y0) | (f2b(y1) << 16);
    w.y = f2b(y2) | (f2b(y3) << 16);
    *(uint2*)(xn + ((size_t)l * S_NS + s) * D_ + lane * 4) = w;
}

// ------------- Projections: xn @ W^T -> q,k,g bf16 (L,H,S,C); v f16 (L,H,C,S) -------------
__global__ __launch_bounds__(256) void proj_kernel(
    const unsigned short* __restrict__ xn,
    const unsigned short* __restrict__ wbf,   // 4 matrices, bf16, 65536 each
    const float* __restrict__ bg,
    unsigned short* __restrict__ qb, unsigned short* __restrict__ kb,
    unsigned short* __restrict__ vb, unsigned short* __restrict__ gb)
{
    int tid  = threadIdx.x;
    int lane = tid & 63, wave = tid >> 6;
    int quad = lane >> 4, l16 = lane & 15;
    int m0   = blockIdx.x * 64 + wave * 16;
    int mat  = blockIdx.y;
    const unsigned short* W = wbf + (size_t)mat * 65536;

    f32x4_t acc[16];
#pragma unroll
    for (int i = 0; i < 16; ++i) acc[i] = (f32x4_t){0.f, 0.f, 0.f, 0.f};

    const unsigned short* arow = xn + (size_t)(m0 + l16) * D_ + quad * 8;
    const unsigned short* brow = W  + (size_t)l16 * D_ + quad * 8;

    for (int ks = 0; ks < 256; ks += 32) {
        bf16x8_t af = *(const bf16x8_t*)(arow + ks);
#pragma unroll
        for (int i = 0; i < 16; ++i) {
            bf16x8_t bf = *(const bf16x8_t*)(brow + (size_t)i * 16 * D_ + ks);
            acc[i] = __builtin_amdgcn_mfma_f32_16x16x32_bf16(af, bf, acc[i], 0, 0, 0);
        }
    }

    const float qscale = 0.17677669529663687f;  // 1/sqrt(32)
#pragma unroll
    for (int i = 0; i < 16; ++i) {
        int n = i * 16 + l16;          // output col 0..255
        int h = n >> 5, c = n & 31;
        float bgn = (mat == 3) ? bg[n] : 0.0f;
#pragma unroll
        for (int r = 0; r < 4; ++r) {
            int mrow = m0 + quad * 4 + r;
            int l = mrow >> 8, s = mrow & 255;
            float v = acc[i][r];
            if (mat == 0) {
                qb[((size_t)(l * H_ + h) * S_NS + s) * C_ + c] = (unsigned short)f2b(v * qscale);
            } else if (mat == 1) {
                kb[((size_t)(l * H_ + h) * S_NS + s) * C_ + c] = (unsigned short)f2b(v);
            } else if (mat == 2) {
                vb[((size_t)(l * H_ + h) * C_ + c) * S_NS + s] = f2h(v);   // V^T, f16
            } else {
                float z = v + bgn;
                gb[((size_t)(l * H_ + h) * S_NS + s) * C_ + c] =
                    (unsigned short)f2b(1.0f / (1.0f + __expf(-z)));
            }
        }
    }
}

// ------------- MFMA attention per (l,h) -------------
#define KP 40    // K LDS row stride (bf16 elems), pad breaks bank alignment
#define VP 264   // V^T LDS row stride (f16 elems), 16B-aligned rows

__global__ __launch_bounds__(256) void attn_kernel(
    const unsigned short* __restrict__ qb, const unsigned short* __restrict__ kb,
    const unsigned short* __restrict__ vb, const unsigned short* __restrict__ gb,
    const int* __restrict__ seq_pad, const int* __restrict__ res_pad,
    unsigned short* __restrict__ ctxg)
{
    __shared__ __align__(16) unsigned short Klds[S_NS * KP];   // 20480 B
    __shared__ __align__(16) unsigned short Vlds[C_ * VP];     // 16896 B
    __shared__ unsigned int padm[16];
    __shared__ int flagall;
    __shared__ float invb[64];

    int tid  = threadIdx.x;
    int lane = tid & 63, wave = tid >> 6;
    int quad = lane >> 4, l16 = lane & 15;
    int lh = blockIdx.x, l = lh >> 3, h = lh & 7;
    size_t base = (size_t)lh * (S_NS * C_);

    // stage K: (S,C) bf16 rows -> padded LDS rows
    const uint4* ksrc = (const uint4*)(kb + base);
#pragma unroll
    for (int i = 0; i < 4; ++i) {
        int idx = i * 256 + tid;            // 8 elems each
        int s = idx >> 2, c8 = (idx & 3) * 8;
        *(uint4*)(Klds + s * KP + c8) = ksrc[idx];
    }
    // stage V^T: (C,S) f16 rows -> padded LDS rows
    const uint4* vsrc = (const uint4*)(vb + base);
#pragma unroll
    for (int i = 0; i < 4; ++i) {
        int idx = i * 256 + tid;
        int c = idx >> 5, s8 = (idx & 31) * 8;
        *(uint4*)(Vlds + c * VP + s8) = vsrc[idx];
    }
    // key-pad bitmasks: padm[t%16] bit (t/16) = seq_pad[t]
    if (tid < 16) {
        unsigned int pm = 0;
        for (int mt = 0; mt < 16; ++mt)
            pm |= (seq_pad[mt * 16 + tid] != 0 ? 1u : 0u) << mt;
        padm[tid] = pm;
    }
    __syncthreads();
    if (tid == 0) {
        unsigned int a = 0xFFFFu;
        for (int i = 0; i < 16; ++i) a &= padm[i];
        // uniform bias (all keys masked, or whole residue masked) == no bias
        flagall = (res_pad[l] != 0) || (a == 0xFFFFu);
    }
    __syncthreads();

    unsigned int keep[4];
#pragma unroll
    for (int r = 0; r < 4; ++r)
        keep[r] = flagall ? 0xFFFFu : (~padm[quad * 4 + r] & 0xFFFFu);

    const float LOG2E = 1.4426950408889634f;

    for (int qt = 0; qt < 4; ++qt) {
        int sb = wave * 64 + qt * 16;       // query-tile base
        // Q frag from global (L2-hot): B[n=s][k=c]
        bf16x8_t qf = *(const bf16x8_t*)(qb + base + (size_t)(sb + l16) * C_ + quad * 8);
        // S^T tiles: A=K (m=t), B=Q (n=s); C-layout: col=s=l16, row=t=quad*4+reg
        f32x4_t acc[16];
#pragma unroll
        for (int kt = 0; kt < 16; ++kt) {
            bf16x8_t kf = *(const bf16x8_t*)(Klds + (kt * 16 + l16) * KP + quad * 8);
            acc[kt] = __builtin_amdgcn_mfma_f32_16x16x32_bf16(kf, qf, (f32x4_t){0.f,0.f,0.f,0.f}, 0, 0, 0);
        }
        // softmax over keys (regs + quad shuffles); max over unbiased logits is
        // valid: probs are shift-invariant, masked entries get p=0 below
        float mx = -3.0e38f;
#pragma unroll
        for (int kt = 0; kt < 16; ++kt) {
            mx = fmaxf(mx, fmaxf(fmaxf(acc[kt][0], acc[kt][1]), fmaxf(acc[kt][2], acc[kt][3])));
        }
        mx = fmaxf(mx, __shfl_xor(mx, 16, 64));
        mx = fmaxf(mx, __shfl_xor(mx, 32, 64));
        float mk = mx * LOG2E;
        float sumv = 0.0f;
#pragma unroll
        for (int kt = 0; kt < 16; ++kt) {
#pragma unroll
            for (int r = 0; r < 4; ++r) {
                float e = __builtin_amdgcn_exp2f(acc[kt][r] * LOG2E - mk);
                e = ((keep[r] >> kt) & 1u) ? e : 0.0f;   // masked key -> exactly 0 (matches ref underflow)
                acc[kt][r] = e;
                sumv += e;
            }
        }
        sumv += __shfl_xor(sumv, 16, 64);
        sumv += __shfl_xor(sumv, 32, 64);
        float inv = 1.0f / sumv;            // > 0 structurally
        if (quad == 0) invb[wave * 16 + l16] = inv;   // broadcast s-indexed inv within wave

        // P^T C-layout rows (quad*4+r) == 16x16x16 A-operand k (quad*4+j): pack direct
        half4_t pf[16];
#pragma unroll
        for (int kt = 0; kt < 16; ++kt) {
            half4_t t;
            t[0] = (_Float16)acc[kt][0]; t[1] = (_Float16)acc[kt][1];
            t[2] = (_Float16)acc[kt][2]; t[3] = (_Float16)acc[kt][3];
            pf[kt] = t;
        }
        // PV: D[m=s][n=c] += P[s][t] * V[t][c]; B[n=c][k=t] from V^T LDS
        f32x4_t c0 = (f32x4_t){0.f,0.f,0.f,0.f}, c1 = (f32x4_t){0.f,0.f,0.f,0.f};
#pragma unroll
        for (int kt = 0; kt < 16; ++kt) {
            half4_t v0 = *(const half4_t*)(Vlds + l16 * VP        + kt * 16 + quad * 4);
            half4_t v1 = *(const half4_t*)(Vlds + (16 + l16) * VP + kt * 16 + quad * 4);
            c0 = __builtin_amdgcn_mfma_f32_16x16x16f16(pf[kt], v0, c0, 0, 0, 0);
            c1 = __builtin_amdgcn_mfma_f32_16x16x16f16(pf[kt], v1, c1, 0, 0, 0);
        }
        // epilogue: ctx * inv * g -> ctxg (L,S,D) bf16. D-layout: col=c=l16, row=s=quad*4+r
#pragma unroll
        for (int r = 0; r < 4; ++r) {
            int s = sb + quad * 4 + r;
            float iv = invb[wave * 16 + quad * 4 + r];
            float g0 = bflo((unsigned int)gb[base + (size_t)s * C_ + l16]);
            float g1 = bflo((unsigned int)gb[base + (size_t)s * C_ + 16 + l16]);
            unsigned short* op = ctxg + (size_t)(l * S_NS + s) * D_ + h * C_;
            op[l16]      = (unsigned short)f2b(c0[r] * iv * g0);
            op[16 + l16] = (unsigned short)f2b(c1[r] * iv * g1);
        }
    }
}

// ------------- Output projection: ctxg @ wo^T + bo -> out fp32 (S,L,D) -------------
__global__ __launch_bounds__(256) void out_kernel(
    const unsigned short* __restrict__ ctxg,
    const unsigned short* __restrict__ wob,   // bf16 wo
    const float* __restrict__ bo,
    float* __restrict__ out)
{
    int tid  = threadIdx.x;
    int lane = tid & 63, wave = tid >> 6;
    int quad = lane >> 4, l16 = lane & 15;
    int m0   = blockIdx.x * 64 + wave * 16;

    f32x4_t acc[16];
#pragma unroll
    for (int i = 0; i < 16; ++i) acc[i] = (f32x4_t){0.f, 0.f, 0.f, 0.f};

    const unsigned short* arow = ctxg + (size_t)(m0 + l16) * D_ + quad * 8;
    const unsigned short* brow = wob  + (size_t)l16 * D_ + quad * 8;

    for (int ks = 0; ks < 256; ks += 32) {
        bf16x8_t af = *(const bf16x8_t*)(arow + ks);
#pragma unroll
        for (int i = 0; i < 16; ++i) {
            bf16x8_t bf = *(const bf16x8_t*)(brow + (size_t)i * 16 * D_ + ks);
            acc[i] = __builtin_amdgcn_mfma_f32_16x16x32_bf16(af, bf, acc[i], 0, 0, 0);
        }
    }

#pragma unroll
    for (int i = 0; i < 16; ++i) {
        int n = i * 16 + l16;
        float bias = bo[n];
#pragma unroll
        for (int r = 0; r < 4; ++r) {
            int mrow = m0 + quad * 4 + r;
            int l = mrow >> 8, s = mrow & 255;
            out[((size_t)s * L_NR + l) * D_ + n] = acc[i][r] + bias;
        }
    }
}

extern "C" void kernel_launch(void* const* d_in, const int* in_sizes, int n_in,
                              void* d_out, int out_size, void* d_ws, size_t ws_size,
                              hipStream_t stream) {
    const float* m     = (const float*)d_in[0];
    const int* seq_pad = (const int*)d_in[1];
    const int* res_pad = (const int*)d_in[2];
    const float* lns   = (const float*)d_in[3];
    const float* lnb   = (const float*)d_in[4];
    const float* wq    = (const float*)d_in[5];
    const float* wk    = (const float*)d_in[6];
    const float* wv    = (const float*)d_in[7];
    const float* wg    = (const float*)d_in[8];
    const float* bg    = (const float*)d_in[9];
    const float* wo    = (const float*)d_in[10];
    const float* bo    = (const float*)d_in[11];
    float* out         = (float*)d_out;

    const size_t NE = (size_t)L_NR * S_NS * D_;   // 12,582,912 elements
    unsigned short* xn = (unsigned short*)d_ws;   // bf16 (L,S,D); reused as ctxg
    unsigned short* qb = xn + NE;
    unsigned short* kb = qb + NE;
    unsigned short* vb = kb + NE;                 // f16 (L,H,C,S)
    unsigned short* gb = vb + NE;
    unsigned short* wbf = gb + NE;                // 5 x 65536 bf16 weights
    unsigned short* ctxg = xn;                    // attn no longer needs xn

    convw_kernel<<<dim3(64, 5), 256, 0, stream>>>(wq, wk, wv, wg, wo, wbf);
    ln_kernel<<<12288, 256, 0, stream>>>(m, lns, lnb, xn);
    proj_kernel<<<dim3(768, 4), 256, 0, stream>>>(xn, wbf, bg, qb, kb, vb, gb);
    attn_kernel<<<L_NR * H_, 256, 0, stream>>>(qb, kb, vb, gb, seq_pad, res_pad, ctxg);
    out_kernel<<<768, 256, 0, stream>>>(ctxg, wbf + 4 * 65536, bo, out);
}

// Round 5
// 315.977 us; speedup vs baseline: 2.1973x; 1.5024x over previous
//
#include <hip/hip_runtime.h>
#include <stdint.h>

#define L_NR 192
#define S_NS 256
#define D_   256
#define H_   8
#define C_   32

typedef __bf16    bf16x8_t __attribute__((ext_vector_type(8)));
typedef _Float16  half4_t  __attribute__((ext_vector_type(4)));
typedef float     f32x4_t  __attribute__((ext_vector_type(4)));

__device__ __forceinline__ float bflo(unsigned int u) { return __uint_as_float(u << 16); }
__device__ __forceinline__ float bfhi(unsigned int u) { return __uint_as_float(u & 0xffff0000u); }
__device__ __forceinline__ unsigned int f2b(float f) {
    unsigned int x = __float_as_uint(f);
    return (x + 0x7fffu + ((x >> 16) & 1u)) >> 16;   // RNE
}
__device__ __forceinline__ unsigned short f2h(float f) {
    union { _Float16 h; unsigned short u; } cv; cv.h = (_Float16)f; return cv.u;
}

// ---- Convert 5 fp32 weight matrices (256x256) to bf16 in workspace ----
__global__ __launch_bounds__(256) void convw_kernel(
    const float* __restrict__ wq, const float* __restrict__ wk,
    const float* __restrict__ wv, const float* __restrict__ wg,
    const float* __restrict__ wo, unsigned short* __restrict__ dst)
{
    int mat = blockIdx.y;
    const float* src = (mat == 0) ? wq : (mat == 1) ? wk : (mat == 2) ? wv
                     : (mat == 3) ? wg : wo;
    int i = (blockIdx.x * 256 + threadIdx.x) * 4;
    float4 v = *(const float4*)(src + i);
    uint2 w;
    w.x = f2b(v.x) | (f2b(v.y) << 16);
    w.y = f2b(v.z) | (f2b(v.w) << 16);
    *(uint2*)(dst + (size_t)mat * 65536 + i) = w;
}

// ---------------- LayerNorm: m fp32 (S,L,D) -> xn bf16 (L,S,D) ----------------
__global__ __launch_bounds__(256) void ln_kernel(
    const float* __restrict__ m,
    const float* __restrict__ lns,
    const float* __restrict__ lnb,
    unsigned short* __restrict__ xn)
{
    int tid = threadIdx.x;
    int lane = tid & 63, wave = tid >> 6;
    int r = blockIdx.x * 4 + wave;          // r = s*L + l
    int s = r / L_NR, l = r % L_NR;

    float4 x = ((const float4*)(m + (size_t)r * D_))[lane];

    float sum = x.x + x.y + x.z + x.w;
    float ss  = x.x*x.x + x.y*x.y + x.z*x.z + x.w*x.w;
#pragma unroll
    for (int off = 32; off > 0; off >>= 1) {
        sum += __shfl_xor(sum, off, 64);
        ss  += __shfl_xor(ss,  off, 64);
    }
    float mean = sum * (1.0f/256.0f);
    float var  = ss  * (1.0f/256.0f) - mean * mean;
    float rstd = rsqrtf(fmaxf(var, 0.0f) + 1e-5f);

    float4 sc = ((const float4*)lns)[lane];
    float4 bi = ((const float4*)lnb)[lane];

    float y0 = (x.x - mean) * rstd * sc.x + bi.x;
    float y1 = (x.y - mean) * rstd * sc.y + bi.y;
    float y2 = (x.z - mean) * rstd * sc.z + bi.z;
    float y3 = (x.w - mean) * rstd * sc.w + bi.w;

    uint2 w;
    w.x = f2b(y0) | (f2b(y1) << 16);
    w.y = f2b(y2) | (f2b(y3) << 16);
    *(uint2*)(xn + ((size_t)l * S_NS + s) * D_ + lane * 4) = w;
}

// ------------- Projections (W-stationary): xn @ W^T -------------
// grid (192, 16): x = 256-row tile; y = mat*4 + nchunk (64 cols).
// W chunk (64x256 bf16 = 32 KB) staged in LDS once; k-loop = ds_read + MFMA only.
// LDS layout: elem = ks*2048 + kq*512 + ((n + ks*4 + kq) & 63)*8  (bank swizzle)
__global__ __launch_bounds__(256) void proj_kernel(
    const unsigned short* __restrict__ xn,
    const unsigned short* __restrict__ wbf,   // 4 matrices, bf16, 65536 each
    const float* __restrict__ bg,
    unsigned short* __restrict__ qb, unsigned short* __restrict__ kb,
    unsigned short* __restrict__ vb, unsigned short* __restrict__ gb)
{
    __shared__ __align__(16) unsigned short Bl[16384];   // 32 KB

    int tid  = threadIdx.x;
    int lane = tid & 63, wave = tid >> 6;
    int quad = lane >> 4, l16 = lane & 15;
    int mat = blockIdx.y >> 2;
    int n0  = (blockIdx.y & 3) * 64;
    const unsigned short* W = wbf + (size_t)mat * 65536 + (size_t)n0 * 256;

    // stage W chunk: coalesced reads (c = n*32 + kk), swizzled LDS writes
#pragma unroll
    for (int j = 0; j < 8; ++j) {
        int c  = j * 256 + tid;
        int n  = c >> 5, kk = c & 31;
        int ks = kk >> 2, kq = kk & 3;
        uint4 d = *(const uint4*)(W + n * 256 + kk * 8);
        *(uint4*)&Bl[ks * 2048 + kq * 512 + (((n + kk) & 63) * 8)] = d;
    }
    __syncthreads();

    int row0 = blockIdx.x * 256 + wave * 64;
    const unsigned short* arow = xn + (size_t)(row0 + l16) * D_ + quad * 8;

    f32x4_t acc[4][4];
#pragma unroll
    for (int mt = 0; mt < 4; ++mt)
#pragma unroll
        for (int nt = 0; nt < 4; ++nt) acc[mt][nt] = (f32x4_t){0.f,0.f,0.f,0.f};

    bf16x8_t a_cur[4], a_nxt[4];
#pragma unroll
    for (int mt = 0; mt < 4; ++mt) a_cur[mt] = *(const bf16x8_t*)(arow + mt * 16 * D_);

#pragma unroll
    for (int ks = 0; ks < 8; ++ks) {
        if (ks < 7) {
#pragma unroll
            for (int mt = 0; mt < 4; ++mt)
                a_nxt[mt] = *(const bf16x8_t*)(arow + mt * 16 * D_ + (ks + 1) * 32);
        }
#pragma unroll
        for (int nt = 0; nt < 4; ++nt) {
            int n = nt * 16 + l16;
            bf16x8_t bfr = *(const bf16x8_t*)&Bl[ks * 2048 + quad * 512 +
                                                 (((n + ks * 4 + quad) & 63) * 8)];
#pragma unroll
            for (int mt = 0; mt < 4; ++mt)
                acc[mt][nt] = __builtin_amdgcn_mfma_f32_16x16x32_bf16(a_cur[mt], bfr, acc[mt][nt], 0, 0, 0);
        }
#pragma unroll
        for (int mt = 0; mt < 4; ++mt) a_cur[mt] = a_nxt[mt];
    }

    const float qscale = 0.17677669529663687f;  // 1/sqrt(32)
#pragma unroll
    for (int nt = 0; nt < 4; ++nt) {
        int n = n0 + nt * 16 + l16;
        int h = n >> 5, c = n & 31;
        float bgn = (mat == 3) ? bg[n] : 0.0f;
#pragma unroll
        for (int mt = 0; mt < 4; ++mt) {
#pragma unroll
            for (int r = 0; r < 4; ++r) {
                int mrow = row0 + mt * 16 + quad * 4 + r;
                int l = mrow >> 8, s = mrow & 255;
                float v = acc[mt][nt][r];
                if (mat == 0) {
                    qb[((size_t)(l * H_ + h) * S_NS + s) * C_ + c] = (unsigned short)f2b(v * qscale);
                } else if (mat == 1) {
                    kb[((size_t)(l * H_ + h) * S_NS + s) * C_ + c] = (unsigned short)f2b(v);
                } else if (mat == 2) {
                    vb[((size_t)(l * H_ + h) * C_ + c) * S_NS + s] = f2h(v);   // V^T, f16
                } else {
                    float z = v + bgn;
                    gb[((size_t)(l * H_ + h) * S_NS + s) * C_ + c] =
                        (unsigned short)f2b(1.0f / (1.0f + __expf(-z)));
                }
            }
        }
    }
}

// ------------- MFMA attention per (l,h) -------------
#define KP 40    // K LDS row stride (bf16 elems)
#define VP 264   // V^T LDS row stride (f16 elems)

__global__ __launch_bounds__(256) void attn_kernel(
    const unsigned short* __restrict__ qb, const unsigned short* __restrict__ kb,
    const unsigned short* __restrict__ vb, const unsigned short* __restrict__ gb,
    const int* __restrict__ seq_pad, const int* __restrict__ res_pad,
    unsigned short* __restrict__ ctxg)
{
    __shared__ __align__(16) unsigned short Klds[S_NS * KP];
    __shared__ __align__(16) unsigned short Vlds[C_ * VP];
    __shared__ unsigned int padm[16];
    __shared__ int flagall;
    __shared__ float invb[64];

    int tid  = threadIdx.x;
    int lane = tid & 63, wave = tid >> 6;
    int quad = lane >> 4, l16 = lane & 15;
    int lh = blockIdx.x, l = lh >> 3, h = lh & 7;
    size_t base = (size_t)lh * (S_NS * C_);

    const uint4* ksrc = (const uint4*)(kb + base);
#pragma unroll
    for (int i = 0; i < 4; ++i) {
        int idx = i * 256 + tid;
        int s = idx >> 2, c8 = (idx & 3) * 8;
        *(uint4*)(Klds + s * KP + c8) = ksrc[idx];
    }
    const uint4* vsrc = (const uint4*)(vb + base);
#pragma unroll
    for (int i = 0; i < 4; ++i) {
        int idx = i * 256 + tid;
        int c = idx >> 5, s8 = (idx & 31) * 8;
        *(uint4*)(Vlds + c * VP + s8) = vsrc[idx];
    }
    if (tid < 16) {
        unsigned int pm = 0;
        for (int mt = 0; mt < 16; ++mt)
            pm |= (seq_pad[mt * 16 + tid] != 0 ? 1u : 0u) << mt;
        padm[tid] = pm;
    }
    __syncthreads();
    if (tid == 0) {
        unsigned int a = 0xFFFFu;
        for (int i = 0; i < 16; ++i) a &= padm[i];
        flagall = (res_pad[l] != 0) || (a == 0xFFFFu);
    }
    __syncthreads();

    unsigned int keep[4];
#pragma unroll
    for (int r = 0; r < 4; ++r)
        keep[r] = flagall ? 0xFFFFu : (~padm[quad * 4 + r] & 0xFFFFu);

    const float LOG2E = 1.4426950408889634f;

    for (int qt = 0; qt < 4; ++qt) {
        int sb = wave * 64 + qt * 16;
        bf16x8_t qf = *(const bf16x8_t*)(qb + base + (size_t)(sb + l16) * C_ + quad * 8);
        f32x4_t acc[16];
#pragma unroll
        for (int kt = 0; kt < 16; ++kt) {
            bf16x8_t kf = *(const bf16x8_t*)(Klds + (kt * 16 + l16) * KP + quad * 8);
            acc[kt] = __builtin_amdgcn_mfma_f32_16x16x32_bf16(kf, qf, (f32x4_t){0.f,0.f,0.f,0.f}, 0, 0, 0);
        }
        float mx = -3.0e38f;
#pragma unroll
        for (int kt = 0; kt < 16; ++kt)
            mx = fmaxf(mx, fmaxf(fmaxf(acc[kt][0], acc[kt][1]), fmaxf(acc[kt][2], acc[kt][3])));
        mx = fmaxf(mx, __shfl_xor(mx, 16, 64));
        mx = fmaxf(mx, __shfl_xor(mx, 32, 64));
        float mk = mx * LOG2E;
        float sumv = 0.0f;
#pragma unroll
        for (int kt = 0; kt < 16; ++kt) {
#pragma unroll
            for (int r = 0; r < 4; ++r) {
                float e = __builtin_amdgcn_exp2f(acc[kt][r] * LOG2E - mk);
                e = ((keep[r] >> kt) & 1u) ? e : 0.0f;
                acc[kt][r] = e;
                sumv += e;
            }
        }
        sumv += __shfl_xor(sumv, 16, 64);
        sumv += __shfl_xor(sumv, 32, 64);
        float inv = 1.0f / sumv;
        if (quad == 0) invb[wave * 16 + l16] = inv;

        half4_t pf[16];
#pragma unroll
        for (int kt = 0; kt < 16; ++kt) {
            half4_t t;
            t[0] = (_Float16)acc[kt][0]; t[1] = (_Float16)acc[kt][1];
            t[2] = (_Float16)acc[kt][2]; t[3] = (_Float16)acc[kt][3];
            pf[kt] = t;
        }
        f32x4_t c0 = (f32x4_t){0.f,0.f,0.f,0.f}, c1 = (f32x4_t){0.f,0.f,0.f,0.f};
#pragma unroll
        for (int kt = 0; kt < 16; ++kt) {
            half4_t v0 = *(const half4_t*)(Vlds + l16 * VP        + kt * 16 + quad * 4);
            half4_t v1 = *(const half4_t*)(Vlds + (16 + l16) * VP + kt * 16 + quad * 4);
            c0 = __builtin_amdgcn_mfma_f32_16x16x16f16(pf[kt], v0, c0, 0, 0, 0);
            c1 = __builtin_amdgcn_mfma_f32_16x16x16f16(pf[kt], v1, c1, 0, 0, 0);
        }
#pragma unroll
        for (int r = 0; r < 4; ++r) {
            int s = sb + quad * 4 + r;
            float iv = invb[wave * 16 + quad * 4 + r];
            float g0 = bflo((unsigned int)gb[base + (size_t)s * C_ + l16]);
            float g1 = bflo((unsigned int)gb[base + (size_t)s * C_ + 16 + l16]);
            unsigned short* op = ctxg + (size_t)(l * S_NS + s) * D_ + h * C_;
            op[l16]      = (unsigned short)f2b(c0[r] * iv * g0);
            op[16 + l16] = (unsigned short)f2b(c1[r] * iv * g1);
        }
    }
}

// ------------- Output projection (W-stationary): ctxg @ wo^T + bo -> out fp32 (S,L,D) -------------
__global__ __launch_bounds__(256) void out_kernel(
    const unsigned short* __restrict__ ctxg,
    const unsigned short* __restrict__ wob,   // bf16 wo
    const float* __restrict__ bo,
    float* __restrict__ out)
{
    __shared__ __align__(16) unsigned short Bl[16384];   // 32 KB

    int tid  = threadIdx.x;
    int lane = tid & 63, wave = tid >> 6;
    int quad = lane >> 4, l16 = lane & 15;
    int n0   = blockIdx.y * 64;
    const unsigned short* W = wob + (size_t)n0 * 256;

#pragma unroll
    for (int j = 0; j < 8; ++j) {
        int c  = j * 256 + tid;
        int n  = c >> 5, kk = c & 31;
        int ks = kk >> 2, kq = kk & 3;
        uint4 d = *(const uint4*)(W + n * 256 + kk * 8);
        *(uint4*)&Bl[ks * 2048 + kq * 512 + (((n + kk) & 63) * 8)] = d;
    }
    __syncthreads();

    int row0 = blockIdx.x * 256 + wave * 64;
    const unsigned short* arow = ctxg + (size_t)(row0 + l16) * D_ + quad * 8;

    f32x4_t acc[4][4];
#pragma unroll
    for (int mt = 0; mt < 4; ++mt)
#pragma unroll
        for (int nt = 0; nt < 4; ++nt) acc[mt][nt] = (f32x4_t){0.f,0.f,0.f,0.f};

    bf16x8_t a_cur[4], a_nxt[4];
#pragma unroll
    for (int mt = 0; mt < 4; ++mt) a_cur[mt] = *(const bf16x8_t*)(arow + mt * 16 * D_);

#pragma unroll
    for (int ks = 0; ks < 8; ++ks) {
        if (ks < 7) {
#pragma unroll
            for (int mt = 0; mt < 4; ++mt)
                a_nxt[mt] = *(const bf16x8_t*)(arow + mt * 16 * D_ + (ks + 1) * 32);
        }
#pragma unroll
        for (int nt = 0; nt < 4; ++nt) {
            int n = nt * 16 + l16;
            bf16x8_t bfr = *(const bf16x8_t*)&Bl[ks * 2048 + quad * 512 +
                                                 (((n + ks * 4 + quad) & 63) * 8)];
#pragma unroll
            for (int mt = 0; mt < 4; ++mt)
                acc[mt][nt] = __builtin_amdgcn_mfma_f32_16x16x32_bf16(a_cur[mt], bfr, acc[mt][nt], 0, 0, 0);
        }
#pragma unroll
        for (int mt = 0; mt < 4; ++mt) a_cur[mt] = a_nxt[mt];
    }

#pragma unroll
    for (int nt = 0; nt < 4; ++nt) {
        int n = n0 + nt * 16 + l16;
        float bias = bo[n];
#pragma unroll
        for (int mt = 0; mt < 4; ++mt) {
#pragma unroll
            for (int r = 0; r < 4; ++r) {
                int mrow = row0 + mt * 16 + quad * 4 + r;
                int l = mrow >> 8, s = mrow & 255;
                out[((size_t)s * L_NR + l) * D_ + n] = acc[mt][nt][r] + bias;
            }
        }
    }
}

extern "C" void kernel_launch(void* const* d_in, const int* in_sizes, int n_in,
                              void* d_out, int out_size, void* d_ws, size_t ws_size,
                              hipStream_t stream) {
    const float* m     = (const float*)d_in[0];
    const int* seq_pad = (const int*)d_in[1];
    const int* res_pad = (const int*)d_in[2];
    const float* lns   = (const float*)d_in[3];
    const float* lnb   = (const float*)d_in[4];
    const float* wq    = (const float*)d_in[5];
    const float* wk    = (const float*)d_in[6];
    const float* wv    = (const float*)d_in[7];
    const float* wg    = (const float*)d_in[8];
    const float* bg    = (const float*)d_in[9];
    const float* wo    = (const float*)d_in[10];
    const float* bo    = (const float*)d_in[11];
    float* out         = (float*)d_out;

    const size_t NE = (size_t)L_NR * S_NS * D_;   // 12,582,912 elements
    unsigned short* xn = (unsigned short*)d_ws;   // bf16 (L,S,D); reused as ctxg
    unsigned short* qb = xn + NE;
    unsigned short* kb = qb + NE;
    unsigned short* vb = kb + NE;                 // f16 (L,H,C,S)
    unsigned short* gb = vb + NE;
    unsigned short* wbf = gb + NE;                // 5 x 65536 bf16 weights
    unsigned short* ctxg = xn;                    // attn no longer needs xn

    convw_kernel<<<dim3(64, 5), 256, 0, stream>>>(wq, wk, wv, wg, wo, wbf);
    ln_kernel<<<12288, 256, 0, stream>>>(m, lns, lnb, xn);
    proj_kernel<<<dim3(192, 16), 256, 0, stream>>>(xn, wbf, bg, qb, kb, vb, gb);
    attn_kernel<<<L_NR * H_, 256, 0, stream>>>(qb, kb, vb, gb, seq_pad, res_pad, ctxg);
    out_kernel<<<dim3(192, 4), 256, 0, stream>>>(ctxg, wbf + 4 * 65536, bo, out);
}